// Round 1
// 415.619 us; speedup vs baseline: 1.0091x; 1.0091x over previous
//
#include <hip/hip_runtime.h>
#include <math.h>

#define DIM 1024
#define NH 16
#define HD 64
#define BATCH 4
#define SEQ 4096
#define NTOK (BATCH*SEQ)  // 16384

typedef float f32x4 __attribute__((ext_vector_type(4)));
typedef short bf16x8 __attribute__((ext_vector_type(8)));

// LDS dest must be WAVE-UNIFORM base; HW writes base + lane*16B.
#define GLOAD_LDS16(gp, lp)                                                    \
  __builtin_amdgcn_global_load_lds(                                            \
      (const __attribute__((address_space(1))) unsigned int*)(gp),             \
      (__attribute__((address_space(3))) unsigned int*)(lp), 16, 0, 0)

__device__ __forceinline__ unsigned short f2bf(float f) {
  unsigned u = __float_as_uint(f);
  unsigned r = (u + 0x7fffu + ((u >> 16) & 1u)) >> 16;
  return (unsigned short)r;
}
__device__ __forceinline__ float bf2f(unsigned short s) {
  return __uint_as_float((unsigned)s << 16);
}

// ---------------------------------------------------------------------------
// 256x256 8-phase bf16 GEMM (HK-style schedule in plain HIP).
//   C = A[16384,1024] @ B[NT_N*256,1024]^T + bias
// 512 threads = 8 waves (2M x 4N), per-wave 128x64 output (8x4 16x16 frags).
// LDS: ring of 4 K-half slots; slot = A[256][32] + B[256][32] bf16 = 32KB.
// Stage 3 K-halves ahead (global_load_lds, 4 calls/K-half, 12 in flight);
// boundary waits are COUNTED vmcnt(8) (epilogue 8->4->0), raw s_barrier,
// so prefetch loads stay in flight across barriers (T3+T4). setprio(1)
// around each 16-MFMA cluster (T5).
// Chunk-XOR swizzle (proven 0-conflict): row r's k-chunk c stored at LDS
// chunk c^((r>>1)&3); read phase fq = (q8^((fr>>1)&3))*8 -> 2-way = free.
// Slot-overwrite safety: stage of half h+3 (slot (h-1)&3) is issued after
// the h-boundary barrier; all reads of slot (h-1)&3 retired before each
// wave's (h-1) phase-1 MFMA (lgkmcnt), hence before that barrier.
// ---------------------------------------------------------------------------
template <int NT_N, int OUT_BF16>
__global__ __launch_bounds__(512, 2) void gemm256(
    const unsigned short* __restrict__ A,
    const unsigned short* __restrict__ B,
    const float* __restrict__ b0, const float* __restrict__ b1,
    const float* __restrict__ b2,
    void* __restrict__ C0, void* __restrict__ C1, void* __restrict__ C2)
{
    __shared__ unsigned short lds[4][2][8192];   // [slot][A/B][256*32] = 128KB
    const int t    = threadIdx.x;
    const int lane = t & 63;
    const int w    = t >> 6;

    // bijective XCD swizzle (nwg % 8 == 0 for both grids)
    const int cpx = gridDim.x >> 3;
    const int swz = (blockIdx.x & 7) * cpx + (blockIdx.x >> 3);
    const int mi  = swz / NT_N;
    const int ni  = swz % NT_N;
    const int m0  = mi * 256;
    const int n0g = ni * 256;                    // row into concat B

    const int wm = (w >> 2) * 128;
    const int wn = (w & 3) * 64;

    // staging: thread t handles chunk c = j*512+t of a 1024-chunk matrix
    // half-tile; row = j*128 + (t>>2); stores logical k-seg
    // (t&3)^((t>>3)&3) at LDS chunk t&3  [(t>>3)&3 == (row>>1)&3, j-indep]
    const int srow = t >> 2;
    const int sseg = ((t & 3) ^ ((t >> 3) & 3)) * 8;
    const unsigned short* Ag = A + (size_t)(m0 + srow) * 1024 + sseg;
    const unsigned short* Bg = B + (size_t)(n0g + srow) * 1024 + sseg;
    const int ldst = w * 512;                    // wave-uniform LDS chunk base

    // fragment read: row fr's k-chunk q8 sits at LDS chunk q8^((fr>>1)&3)
    const int fr = lane & 15;
    const int fq = ((lane >> 4) ^ ((fr >> 1) & 3)) * 8;

    f32x4 acc[8][4] = {};

#define STAGE_A(hh, j)                                                        \
  GLOAD_LDS16(Ag + (size_t)(j) * 131072 + (size_t)(hh) * 32,                  \
              &lds[(hh) & 3][0][(j) * 4096 + ldst])
#define STAGE_B(hh, j)                                                        \
  GLOAD_LDS16(Bg + (size_t)(j) * 131072 + (size_t)(hh) * 32,                  \
              &lds[(hh) & 3][1][(j) * 4096 + ldst])

#define BOUNDARY(VM)                                                          \
  asm volatile("s_waitcnt vmcnt(" #VM ")" ::: "memory");                      \
  __builtin_amdgcn_s_barrier();                                               \
  asm volatile("" ::: "memory");

#define KHALF(h, DOSTAGE)                                                     \
  {                                                                           \
    const unsigned short* As_ = &lds[(h) & 3][0][0];                          \
    const unsigned short* Bs_ = &lds[(h) & 3][1][0];                          \
    bf16x8 bfr[4], afr[4];                                                    \
    if (DOSTAGE) { STAGE_A((h) + 3, 0); STAGE_A((h) + 3, 1); }                \
    _Pragma("unroll")                                                         \
    for (int nf = 0; nf < 4; ++nf)                                            \
      bfr[nf] = *(const bf16x8*)&Bs_[(wn + nf * 16 + fr) * 32 + fq];          \
    _Pragma("unroll")                                                         \
    for (int mf = 0; mf < 4; ++mf)                                            \
      afr[mf] = *(const bf16x8*)&As_[(wm + mf * 16 + fr) * 32 + fq];          \
    __builtin_amdgcn_s_barrier();                                             \
    asm volatile("s_waitcnt lgkmcnt(0)" ::: "memory");                        \
    __builtin_amdgcn_s_setprio(1);                                            \
    _Pragma("unroll")                                                         \
    for (int mf = 0; mf < 4; ++mf)                                            \
      _Pragma("unroll")                                                       \
      for (int nf = 0; nf < 4; ++nf)                                          \
        acc[mf][nf] = __builtin_amdgcn_mfma_f32_16x16x32_bf16(                \
            afr[mf], bfr[nf], acc[mf][nf], 0, 0, 0);                          \
    __builtin_amdgcn_s_setprio(0);                                            \
    __builtin_amdgcn_s_barrier();                                             \
    asm volatile("" ::: "memory");                                            \
    if (DOSTAGE) { STAGE_B((h) + 3, 0); STAGE_B((h) + 3, 1); }                \
    _Pragma("unroll")                                                         \
    for (int mf = 0; mf < 4; ++mf)                                            \
      afr[mf] = *(const bf16x8*)&As_[(wm + 64 + mf * 16 + fr) * 32 + fq];     \
    __builtin_amdgcn_s_barrier();                                             \
    asm volatile("s_waitcnt lgkmcnt(0)" ::: "memory");                        \
    __builtin_amdgcn_s_setprio(1);                                            \
    _Pragma("unroll")                                                         \
    for (int mf = 0; mf < 4; ++mf)                                            \
      _Pragma("unroll")                                                       \
      for (int nf = 0; nf < 4; ++nf)                                          \
        acc[4 + mf][nf] = __builtin_amdgcn_mfma_f32_16x16x32_bf16(            \
            afr[mf], bfr[nf], acc[4 + mf][nf], 0, 0, 0);                      \
    __builtin_amdgcn_s_setprio(0);                                            \
  }

    // prologue: stage K-halves 0,1,2 (12 loads in flight)
#pragma unroll
    for (int hh = 0; hh < 3; ++hh) {
        STAGE_A(hh, 0); STAGE_A(hh, 1);
        STAGE_B(hh, 0); STAGE_B(hh, 1);
    }

    // main: 32 K-halves (K=1024, 32 cols each); steady-state wait vmcnt(8)
#pragma unroll 1
    for (int h = 0; h < 29; ++h) {
        BOUNDARY(8);
        KHALF(h, 1);
    }
    BOUNDARY(8); KHALF(29, 0);
    BOUNDARY(4); KHALF(30, 0);
    BOUNDARY(0); KHALF(31, 0);

#undef KHALF
#undef BOUNDARY
#undef STAGE_A
#undef STAGE_B

    // epilogue: matrix select (uniform per block); C/D layout col=lane&15,
    // row=(lane>>4)*4+r
    const int mat = ni >> 2;
    const float* bias = (mat == 0) ? b0 : (mat == 1) ? b1 : b2;
    void* Cp = (mat == 0) ? C0 : (mat == 1) ? C1 : C2;
    const int n0 = (ni & 3) * 256;

    const int col = lane & 15;
    const int rq  = (lane >> 4) * 4;
#pragma unroll
    for (int nf = 0; nf < 4; ++nf) {
        int cbase = n0 + wn + nf * 16 + col;
        float bv = bias[cbase];
#pragma unroll
        for (int mf = 0; mf < 8; ++mf) {
            int rbase = m0 + wm + (mf >> 2) * 64 + (mf & 3) * 16 + rq;
#pragma unroll
            for (int r = 0; r < 4; ++r) {
                float val = acc[mf][nf][r] + bv;
                size_t idx = (size_t)(rbase + r) * 1024 + cbase;
                if (OUT_BF16)
                    ((unsigned short*)Cp)[idx] = f2bf(val);
                else
                    ((float*)Cp)[idx] = val;
            }
        }
    }
}

// ---------------------------------------------------------------------------
// fp32 -> bf16 casts
// ---------------------------------------------------------------------------
__global__ __launch_bounds__(256) void cast_bf16(
    const float* __restrict__ src, unsigned short* __restrict__ dst, int n)
{
    int i = (blockIdx.x * 256 + threadIdx.x) * 4;
    if (i >= n) return;
    float4 v = *(const float4*)&src[i];
    ushort2 lo = {f2bf(v.x), f2bf(v.y)};
    ushort2 hi = {f2bf(v.z), f2bf(v.w)};
    *(ushort2*)&dst[i] = lo;
    *(ushort2*)&dst[i + 2] = hi;
}

__global__ __launch_bounds__(256) void cast_bf16_w4(
    const float* __restrict__ s0, const float* __restrict__ s1,
    const float* __restrict__ s2, const float* __restrict__ s3,
    unsigned short* __restrict__ d0, unsigned short* __restrict__ d1,
    unsigned short* __restrict__ d2, unsigned short* __restrict__ d3)
{
    const float* s = (blockIdx.y == 0) ? s0 : (blockIdx.y == 1) ? s1
                    : (blockIdx.y == 2) ? s2 : s3;
    unsigned short* d = (blockIdx.y == 0) ? d0 : (blockIdx.y == 1) ? d1
                       : (blockIdx.y == 2) ? d2 : d3;
    int i = (blockIdx.x * 256 + threadIdx.x) * 4;
    float4 v = *(const float4*)&s[i];
    ushort2 lo = {f2bf(v.x), f2bf(v.y)};
    ushort2 hi = {f2bf(v.z), f2bf(v.w)};
    *(ushort2*)&d[i] = lo;
    *(ushort2*)&d[i + 2] = hi;
}

// ---------------------------------------------------------------------------
// MFMA Performer feature map, in place on bf16 rows of 64.
// ---------------------------------------------------------------------------
__global__ __launch_bounds__(256) void featmap_mfma(
    unsigned short* __restrict__ buf, const float* __restrict__ R)
{
    __shared__ unsigned short Rt[64 * 72];
    const int t = threadIdx.x;
    for (int i = t; i < 4096; i += 256) {
        int n = i >> 6, k = i & 63;
        Rt[n * 72 + k] = f2bf(R[k * 64 + n]);
    }
    __syncthreads();

    const int lane = t & 63;
    const int w = t >> 6;
    const size_t rowbase = (size_t)blockIdx.x * 256 + w * 64;
    const int fr = lane & 15;
    const int fq = (lane >> 4) * 8;

    f32x4 acc[4][4] = {};
    float sqacc[4] = {0.f, 0.f, 0.f, 0.f};

#pragma unroll
    for (int ks = 0; ks < 2; ks++) {
        bf16x8 bfr[4];
#pragma unroll
        for (int nt = 0; nt < 4; nt++)
            bfr[nt] = *(const bf16x8*)&Rt[(nt * 16 + fr) * 72 + ks * 32 + fq];
#pragma unroll
        for (int mt = 0; mt < 4; mt++) {
            bf16x8 a = *(const bf16x8*)
                &buf[(rowbase + mt * 16 + fr) * 64 + ks * 32 + fq];
#pragma unroll
            for (int j = 0; j < 8; j++) {
                float v = bf2f((unsigned short)a[j]);
                sqacc[mt] = fmaf(v, v, sqacc[mt]);
            }
#pragma unroll
            for (int nt = 0; nt < 4; nt++)
                acc[mt][nt] = __builtin_amdgcn_mfma_f32_16x16x32_bf16(
                    a, bfr[nt], acc[mt][nt], 0, 0, 0);
        }
    }
#pragma unroll
    for (int mt = 0; mt < 4; mt++) {
        sqacc[mt] += __shfl_xor(sqacc[mt], 16);
        sqacc[mt] += __shfl_xor(sqacc[mt], 32);
    }

    const int col = lane & 15;
    const int rq  = (lane >> 4) * 4;
#pragma unroll
    for (int mt = 0; mt < 4; mt++) {
#pragma unroll
        for (int r = 0; r < 4; r++) {
            float s = __shfl(sqacc[mt], rq + r);
            size_t row = rowbase + mt * 16 + rq + r;
#pragma unroll
            for (int nt = 0; nt < 4; nt++) {
                float val = acc[mt][nt][r] * 0.125f - s * 0.0078125f;
                buf[row * 64 + nt * 16 + col] = f2bf(__expf(val));
            }
        }
    }
}

// ---------------------------------------------------------------------------
// kv[b,h,m,e] += sum_n k'[n,m] * v[n,e] over a 512-token chunk. bf16 in.
// ---------------------------------------------------------------------------
__global__ __launch_bounds__(256) void kv_accum(
    const unsigned short* __restrict__ kp, const unsigned short* __restrict__ vp,
    float* __restrict__ kv)
{
    __shared__ float Ks[16][68];
    __shared__ float Vs[16][68];
    const int chunk = blockIdx.x;
    const int h = blockIdx.y;
    const int b = blockIdx.z;
    const int t = threadIdx.x;
    const int tx = t & 15, ty = t >> 4;
    float c[4][4] = {};
    const int nbase = b * SEQ + chunk * 512;
    const int nl = t >> 4, seg = t & 15;
    for (int n0 = 0; n0 < 512; n0 += 16) {
        size_t gaddr = (size_t)(nbase + n0 + nl) * DIM + h * 64 + seg * 4;
        ushort4 kq = *(const ushort4*)&kp[gaddr];
        ushort4 vq = *(const ushort4*)&vp[gaddr];
        Ks[nl][seg * 4 + 0] = bf2f(kq.x); Ks[nl][seg * 4 + 1] = bf2f(kq.y);
        Ks[nl][seg * 4 + 2] = bf2f(kq.z); Ks[nl][seg * 4 + 3] = bf2f(kq.w);
        Vs[nl][seg * 4 + 0] = bf2f(vq.x); Vs[nl][seg * 4 + 1] = bf2f(vq.y);
        Vs[nl][seg * 4 + 2] = bf2f(vq.z); Vs[nl][seg * 4 + 3] = bf2f(vq.w);
        __syncthreads();
#pragma unroll
        for (int nn = 0; nn < 16; nn++) {
            float4 a = *(const float4*)&Ks[nn][ty * 4];
            float4 bq = *(const float4*)&Vs[nn][tx * 4];
            float aa[4] = {a.x, a.y, a.z, a.w};
            float bb[4] = {bq.x, bq.y, bq.z, bq.w};
#pragma unroll
            for (int i = 0; i < 4; i++)
#pragma unroll
                for (int j = 0; j < 4; j++)
                    c[i][j] += aa[i] * bb[j];
        }
        __syncthreads();
    }
    float* dst = &kv[(size_t)(b * NH + h) * 64 * 64];
#pragma unroll
    for (int i = 0; i < 4; i++)
#pragma unroll
        for (int j = 0; j < 4; j++)
            atomicAdd(&dst[(ty * 4 + i) * 64 + tx * 4 + j], c[i][j]);
}

// ---------------------------------------------------------------------------
// MFMA attn out: per (b,h), out[n,e] = z[n] * (q'[n,:] @ kv[:,e])
// ---------------------------------------------------------------------------
__global__ __launch_bounds__(256) void attn_out_mfma(
    const unsigned short* __restrict__ qp, const float* __restrict__ kv,
    unsigned short* __restrict__ ob)
{
    __shared__ unsigned short kvT[64 * 72];
    const int t = threadIdx.x;
    const int bh = blockIdx.y;
    const int b = bh >> 4, h = bh & 15;
    const float* kvp = &kv[(size_t)bh * 4096];
    for (int i = t; i < 4096; i += 256) {
        int m = i >> 6, e = i & 63;
        kvT[e * 72 + m] = f2bf(kvp[i]);
    }
    __syncthreads();

    const int lane = t & 63;
    const int w = t >> 6;
    const int rowInSeq = blockIdx.x * 256 + w * 64;
    const int fr = lane & 15;
    const int fq = (lane >> 4) * 8;

    f32x4 acc[4][4] = {};
    float rsum[4] = {0.f, 0.f, 0.f, 0.f};

#pragma unroll
    for (int ks = 0; ks < 2; ks++) {
        bf16x8 bfr[4];
#pragma unroll
        for (int nt = 0; nt < 4; nt++)
            bfr[nt] = *(const bf16x8*)&kvT[(nt * 16 + fr) * 72 + ks * 32 + fq];
#pragma unroll
        for (int mt = 0; mt < 4; mt++) {
            size_t n = (size_t)(b * SEQ + rowInSeq + mt * 16 + fr);
            bf16x8 a = *(const bf16x8*)&qp[n * DIM + h * 64 + ks * 32 + fq];
#pragma unroll
            for (int j = 0; j < 8; j++)
                rsum[mt] += bf2f((unsigned short)a[j]);
#pragma unroll
            for (int nt = 0; nt < 4; nt++)
                acc[mt][nt] = __builtin_amdgcn_mfma_f32_16x16x32_bf16(
                    a, bfr[nt], acc[mt][nt], 0, 0, 0);
        }
    }
#pragma unroll
    for (int mt = 0; mt < 4; mt++) {
        rsum[mt] += __shfl_xor(rsum[mt], 16);
        rsum[mt] += __shfl_xor(rsum[mt], 32);
    }

    const int col = lane & 15;
    const int rq  = (lane >> 4) * 4;
#pragma unroll
    for (int mt = 0; mt < 4; mt++) {
#pragma unroll
        for (int r = 0; r < 4; r++) {
            float s = __shfl(rsum[mt], rq + r);
            float z = 1.f / (s + 1e-8f);
            size_t n = (size_t)(b * SEQ + rowInSeq + mt * 16 + rq + r);
#pragma unroll
            for (int nt = 0; nt < 4; nt++)
                ob[n * DIM + h * 64 + nt * 16 + col] = f2bf(acc[mt][nt][r] * z);
        }
    }
}

extern "C" void kernel_launch(void* const* d_in, const int* in_sizes, int n_in,
                              void* d_out, int out_size, void* d_ws, size_t ws_size,
                              hipStream_t stream) {
    const float* x  = (const float*)d_in[0];
    const float* Wq = (const float*)d_in[1];
    const float* bq = (const float*)d_in[2];
    const float* Wk = (const float*)d_in[3];
    const float* bk = (const float*)d_in[4];
    const float* Wv = (const float*)d_in[5];
    const float* bv = (const float*)d_in[6];
    const float* Wo = (const float*)d_in[7];
    const float* bo = (const float*)d_in[8];
    const float* R  = (const float*)d_in[9];
    float* out = (float*)d_out;

    // workspace — 137 MB. qb/kb contiguous (featmap spans both).
    char* p = (char*)d_ws;
    unsigned short* xb = (unsigned short*)p; p += (size_t)NTOK * DIM * 2;  // 32MB
    unsigned short* qb = (unsigned short*)p; p += (size_t)NTOK * DIM * 2;  // 32MB
    unsigned short* kb = (unsigned short*)p; p += (size_t)NTOK * DIM * 2;  // 32MB
    unsigned short* vb = (unsigned short*)p; p += (size_t)NTOK * DIM * 2;  // 32MB
    float* kvb = (float*)p;                  p += (size_t)BATCH * NH * HD * HD * 4; // 1MB
    unsigned short* wqkv = (unsigned short*)p; p += (size_t)3 * DIM * DIM * 2; // 6MB contig
    unsigned short* wob  = (unsigned short*)p; p += (size_t)DIM * DIM * 2;     // 2MB

    hipMemsetAsync(kvb, 0, (size_t)BATCH * NH * HD * HD * sizeof(float), stream);

    cast_bf16<<<NTOK * DIM / (256 * 4), 256, 0, stream>>>(x, xb, NTOK * DIM);
    cast_bf16_w4<<<dim3(DIM * DIM / (256 * 4), 4), 256, 0, stream>>>(
        Wq, Wk, Wv, Wo,
        wqkv, wqkv + (size_t)DIM * DIM, wqkv + (size_t)2 * DIM * DIM, wob);

    // fused QKV projection: 64 m-tiles x 12 n-tiles = 768 blocks, 512 thr
    gemm256<12, 1><<<768, 512, 0, stream>>>(
        xb, wqkv, bq, bk, bv, qb, kb, vb);

    // feature map over q' and k' in one launch (contiguous rows)
    featmap_mfma<<<2 * NTOK * NH / 256, 256, 0, stream>>>(qb, R);

    kv_accum<<<dim3(8, NH, BATCH), 256, 0, stream>>>(kb, vb, kvb);

    // attn output reuses xb
    attn_out_mfma<<<dim3(SEQ / 256, BATCH * NH), 256, 0, stream>>>(qb, kvb, xb);

    // output projection: 64 x 4 = 256 blocks, fp32 out
    gemm256<4, 0><<<256, 512, 0, stream>>>(
        xb, wob, bo, bo, bo, out, out, out);
}